// Round 6
// baseline (181.755 us; speedup 1.0000x reference)
//
#include <hip/hip_runtime.h>
#include <hip/hip_bf16.h>

#define SS 2048
#define DD 128
#define BB 16
#define LDST 136  // xs staging pad (ushorts)
#define SCT 268   // sc stride: 4-way max on frag-order epilogue reads

typedef short bf16x8 __attribute__((ext_vector_type(8)));
typedef float f32x4 __attribute__((ext_vector_type(4)));
typedef unsigned short ushort_t;

__device__ __forceinline__ unsigned short f2bf(float f) {
  union { float f; unsigned u; } v; v.f = f;
  unsigned r = v.u + 0x7fffu + ((v.u >> 16) & 1u);  // RNE
  return (unsigned short)(r >> 16);
}
__device__ __forceinline__ float fexp2(float x) { return __builtin_amdgcn_exp2f(x); }

// Fragment-major layout: chunk index ((G*4 + ks)*64 + lane), 16 B each.
// G = global 16-row group (b*128 + g), lane = quad*16 + lq holds
// rows[G*16+lq], cols[ks*32+quad*8 .. +8]. A and B frag loads are then
// one coalesced dwordx4 per (G,ks): lane L reads chunk base + L*16.

// ---------------------------------------------------------------------------
// wprep: wt_g = [Wq^T * log2e/sqrt(U) ; Wk^T] bf16 [256][128]. grid 128.
// ---------------------------------------------------------------------------
__global__ __launch_bounds__(256) void wprep(
    const float* __restrict__ Wq, const float* __restrict__ Wk,
    ushort_t* __restrict__ wt_g) {
  int idx = blockIdx.x * 256 + threadIdx.x;  // 0..32767
  int r = idx & 16383, uu = r >> 7, d = r & 127;
  if (idx < 16384)
    wt_g[uu * 128 + d] = f2bf(Wq[d * 128 + uu] * 0.1275174346f);  // log2e/sqrt(128)
  else
    wt_g[(uu + 128) * 128 + d] = f2bf(Wk[d * 128 + uu]);
}

// ---------------------------------------------------------------------------
// qk_gemm: [q|k] = bf16(x) @ wt_g^T, output in FRAG-MAJOR layout.
// grid 512 (64 rows/block), block 256.
// ---------------------------------------------------------------------------
__global__ __launch_bounds__(256, 2) void qk_gemm(
    const float* __restrict__ x, const ushort_t* __restrict__ wt_g,
    uint4* __restrict__ qF, uint4* __restrict__ kF) {
  __shared__ ushort_t xs[64 * LDST];
  __shared__ ushort_t sc[64 * SCT];
  const int tid = threadIdx.x, wave = tid >> 6, lane = tid & 63;
  const int lq = lane & 15, quad = lane >> 4;
  const int m0 = blockIdx.x * 64;

#pragma unroll
  for (int i = 0; i < 8; ++i) {  // stage x: 64x128 fp32 -> bf16
    int idx = i * 256 + tid;
    int row = idx >> 5, c4 = (idx & 31) * 4;
    const float4 v = *(const float4*)(x + (size_t)(m0 + row) * DD + c4);
    ushort4 h;
    h.x = f2bf(v.x); h.y = f2bf(v.y); h.z = f2bf(v.z); h.w = f2bf(v.w);
    *(ushort4*)(&xs[row * LDST + c4]) = h;
  }
  bf16x8 wf[4][4];  // wave's 64 output cols, K=128
#pragma unroll
  for (int nt = 0; nt < 4; ++nt)
#pragma unroll
    for (int ks = 0; ks < 4; ++ks)
      wf[nt][ks] = *(const bf16x8*)(wt_g + (wave * 64 + nt * 16 + lq) * 128 + ks * 32 + quad * 8);
  __syncthreads();

  f32x4 acc[4][4];
#pragma unroll
  for (int mt = 0; mt < 4; ++mt)
#pragma unroll
    for (int nt = 0; nt < 4; ++nt) acc[mt][nt] = (f32x4){0.f, 0.f, 0.f, 0.f};
#pragma unroll
  for (int mt = 0; mt < 4; ++mt) {
    bf16x8 af[4];
#pragma unroll
    for (int ks = 0; ks < 4; ++ks)
      af[ks] = *(const bf16x8*)(&xs[(mt * 16 + lq) * LDST + ks * 32 + quad * 8]);
#pragma unroll
    for (int nt = 0; nt < 4; ++nt)
#pragma unroll
      for (int ks = 0; ks < 4; ++ks)
        acc[mt][nt] = __builtin_amdgcn_mfma_f32_16x16x32_bf16(af[ks], wf[nt][ks], acc[mt][nt], 0, 0, 0);
  }
  // C/D: row = mt*16+quad*4+r, col = wave*64+nt*16+lq
#pragma unroll
  for (int mt = 0; mt < 4; ++mt)
#pragma unroll
    for (int nt = 0; nt < 4; ++nt)
#pragma unroll
      for (int r = 0; r < 4; ++r)
        sc[(mt * 16 + quad * 4 + r) * SCT + wave * 64 + nt * 16 + lq] = f2bf(acc[mt][nt][r]);
  __syncthreads();
  // epilogue: re-read in fragment order, store coalesced frag-major chunks
#pragma unroll
  for (int i = 0; i < 8; ++i) {
    int c = i * 256 + tid;                 // 0..2047
    int lane_c = c & 63, ks_c = (c >> 6) & 3, g_c = (c >> 8) & 3, isk = c >> 10;
    int li = lane_c & 15, qd = lane_c >> 4;
    int col = isk * 128 + ks_c * 32 + qd * 8;
    uint4 v = *(const uint4*)(&sc[(g_c * 16 + li) * SCT + col]);
    size_t G = (size_t)blockIdx.x * 4 + g_c;
    uint4* dst = isk ? kF : qF;
    dst[(G * 4 + ks_c) * 64 + lane_c] = v;
  }
}

// ---------------------------------------------------------------------------
// attn pass 1 & 2.  R5 post-mortem: per-pass time (~22 us) is invariant
// across occupancy 2<->4 waves/SIMD, fused<->split, swizzle on/off, and
// equals K-traffic (268 MB/pass) / ~12 TB/s delivered L2 BW. Theory: the
// L2->CU streaming path is the binding resource -> CUT TRAFFIC.
//
// This version: i=128 rows per block (Q staged in LDS, 32 KB, frag-major
// -> conflict-free ds_read_b128 at lane*16+const; R3 measured 0 bank
// conflicts for this pattern). Each K byte feeds 2x the MFMAs -> K
// traffic per pass halves to 134 MB. Grid 1024 = 16 b x 16 i-blocks x 4
// j-quarters; 4 blocks/CU (LDS 4x34 KB = 136 < 160 KB). Per-wave regs
// ~105 < 128 at (256,4) (a[8]=32 + rowsum/creg=32 + f=16 + addr).
// Plus: j-stream rotation by i-block (de-phases the 16 lockstep K
// streams over the ring -> spreads L2 bank/channel load) and XCD-
// clustered batch mapping (2 MB working set per XCD L2).
// ---------------------------------------------------------------------------
__device__ __forceinline__ void attn_decode(int bx, int& b, int& ii, int& jq) {
  int x = bx & 7, s = bx >> 3;   // dispatcher: wgid%8 -> XCD
  b = x + ((s >> 6) << 3);       // XCD x hosts batches x, x+8
  int r = s & 63;
  ii = r >> 2;                   // i-block 0..15 (128 rows each)
  jq = r & 3;                    // j-quarter 0..3 (32 groups each)
}

__global__ __launch_bounds__(256, 4) void attn_p1(
    const uint4* __restrict__ qF, const uint4* __restrict__ kF,
    float* __restrict__ l) {
  int b, ii, jq;
  attn_decode(blockIdx.x, b, ii, jq);
  const int tid = threadIdx.x, wave = tid >> 6, lane = tid & 63;
  const int lq = lane & 15, quad = lane >> 4;
  __shared__ uint4 qs[2048];        // Q frags, 32 KB: chunk (mt*4+ks)*64+lane
  __shared__ float rs_lds[4][128];

  // stage Q: 32 contiguous chunks for (b, ii) in frag-major qF
  {
    const uint4* qbase = qF + (size_t)(b * 128 + ii * 8) * 4 * 64;
#pragma unroll
    for (int i = 0; i < 8; ++i) qs[i * 256 + tid] = qbase[i * 256 + tid];
  }
  __syncthreads();

  const uint4* qsl = qs + lane;
  const bf16x8* kb = (const bf16x8*)kF + (size_t)b * 128 * 4 * 64 + lane;
  const int rot = ii & 7;

  float rowsum[8][4];
#pragma unroll
  for (int mt = 0; mt < 8; ++mt)
#pragma unroll
    for (int r = 0; r < 4; ++r) rowsum[mt][r] = 0.f;

  const f32x4 z4 = {0.f, 0.f, 0.f, 0.f};
  for (int it = 0; it < 8; ++it) {
    int g = jq * 32 + (((it + rot) & 7) << 2) + wave;
    bf16x8 f[4];
#pragma unroll
    for (int ks = 0; ks < 4; ++ks) f[ks] = kb[((size_t)g * 4 + ks) * 64];
    f32x4 a[8];
    __builtin_amdgcn_s_setprio(1);
#pragma unroll
    for (int mt = 0; mt < 8; ++mt) {
      bf16x8 q0 = *(const bf16x8*)(qsl + (mt * 4 + 0) * 64);
      a[mt] = __builtin_amdgcn_mfma_f32_16x16x32_bf16(q0, f[0], z4, 0, 0, 0);
    }
#pragma unroll
    for (int ks = 1; ks < 4; ++ks)
#pragma unroll
      for (int mt = 0; mt < 8; ++mt) {
        bf16x8 qk = *(const bf16x8*)(qsl + (mt * 4 + ks) * 64);
        a[mt] = __builtin_amdgcn_mfma_f32_16x16x32_bf16(qk, f[ks], a[mt], 0, 0, 0);
      }
    __builtin_amdgcn_s_setprio(0);
#pragma unroll
    for (int mt = 0; mt < 8; ++mt)
#pragma unroll
      for (int r = 0; r < 4; ++r) rowsum[mt][r] += fexp2(a[mt][r]);
  }

  // sum over the 16 j-cols held across lq lanes
#pragma unroll
  for (int d2 = 1; d2 <= 8; d2 <<= 1)
#pragma unroll
    for (int mt = 0; mt < 8; ++mt)
#pragma unroll
      for (int r = 0; r < 4; ++r)
        rowsum[mt][r] += __shfl_xor(rowsum[mt][r], d2, 64);
  if (lq == 0) {
#pragma unroll
    for (int mt = 0; mt < 8; ++mt)
#pragma unroll
      for (int r = 0; r < 4; ++r)
        rs_lds[wave][mt * 16 + quad * 4 + r] = rowsum[mt][r];
  }
  __syncthreads();
  if (tid < 128) {
    float p = rs_lds[0][tid] + rs_lds[1][tid] + rs_lds[2][tid] + rs_lds[3][tid];
    atomicAdd(&l[b * SS + ii * 128 + tid], p);
  }
}

__global__ __launch_bounds__(256, 4) void attn_p2(
    const uint4* __restrict__ qF, const uint4* __restrict__ kF,
    const float* __restrict__ t, const float* __restrict__ theta,
    const float* __restrict__ mu, const float* __restrict__ l,
    float* __restrict__ w) {
  int b, ii, jq;
  attn_decode(blockIdx.x, b, ii, jq);
  const int tid = threadIdx.x, wave = tid >> 6, lane = tid & 63;
  const int lq = lane & 15, quad = lane >> 4;
  __shared__ uint4 qs[2048];        // 32 KB
  __shared__ float c_lds[128];

  {
    const uint4* qbase = qF + (size_t)(b * 128 + ii * 8) * 4 * 64;
#pragma unroll
    for (int i = 0; i < 8; ++i) qs[i * 256 + tid] = qbase[i * 256 + tid];
  }
  if (tid < 128) {
    int gi = ii * 128 + tid;
    float z = theta[gi] - mu[gi] * t[b * SS + gi];
    float tf = 1.f / (1.f + fexp2(-z * 1.44269504f));
    c_lds[tid] = tf / l[b * SS + gi];
  }
  __syncthreads();

  const uint4* qsl = qs + lane;
  float creg[8][4];
#pragma unroll
  for (int mt = 0; mt < 8; ++mt)
#pragma unroll
    for (int r = 0; r < 4; ++r) creg[mt][r] = c_lds[mt * 16 + quad * 4 + r];

  const bf16x8* kb = (const bf16x8*)kF + (size_t)b * 128 * 4 * 64 + lane;
  const int rot = ii & 7;
  const f32x4 z4 = {0.f, 0.f, 0.f, 0.f};

  for (int it = 0; it < 8; ++it) {
    int g = jq * 32 + (((it + rot) & 7) << 2) + wave;
    bf16x8 f[4];
#pragma unroll
    for (int ks = 0; ks < 4; ++ks) f[ks] = kb[((size_t)g * 4 + ks) * 64];
    f32x4 a[8];
    __builtin_amdgcn_s_setprio(1);
#pragma unroll
    for (int mt = 0; mt < 8; ++mt) {
      bf16x8 q0 = *(const bf16x8*)(qsl + (mt * 4 + 0) * 64);
      a[mt] = __builtin_amdgcn_mfma_f32_16x16x32_bf16(q0, f[0], z4, 0, 0, 0);
    }
#pragma unroll
    for (int ks = 1; ks < 4; ++ks)
#pragma unroll
      for (int mt = 0; mt < 8; ++mt) {
        bf16x8 qk = *(const bf16x8*)(qsl + (mt * 4 + ks) * 64);
        a[mt] = __builtin_amdgcn_mfma_f32_16x16x32_bf16(qk, f[ks], a[mt], 0, 0, 0);
      }
    __builtin_amdgcn_s_setprio(0);
    float cs = 0.f;
#pragma unroll
    for (int mt = 0; mt < 8; ++mt)
#pragma unroll
      for (int r = 0; r < 4; ++r) cs = fmaf(creg[mt][r], fexp2(a[mt][r]), cs);
    cs += __shfl_xor(cs, 16, 64);
    cs += __shfl_xor(cs, 32, 64);
    if (lane < 16) atomicAdd(&w[b * SS + g * 16 + lane], cs);
  }
}

// ---------------------------------------------------------------------------
// finalize: v[b,d] = sum_j w[b,j] * x[b,j,d].  grid 512 (64 j per block).
// ---------------------------------------------------------------------------
__global__ __launch_bounds__(256) void finalize(
    const float* __restrict__ x, const float* __restrict__ w,
    float* __restrict__ out) {
  const int b = blockIdx.x >> 5;
  const int j0 = (blockIdx.x & 31) * 64;
  const int tid = threadIdx.x;
  const int d = tid & 127, jo = tid >> 7;
  float acc = 0.f;
  for (int jj = 0; jj < 32; ++jj) {
    int j = j0 + jj * 2 + jo;
    acc = fmaf(w[b * SS + j], x[((size_t)b * SS + j) * DD + d], acc);
  }
  __shared__ float red[256];
  red[tid] = acc;
  __syncthreads();
  if (tid < 128) atomicAdd(&out[b * DD + tid], red[tid] + red[tid + 128]);
}

extern "C" void kernel_launch(void* const* d_in, const int* in_sizes, int n_in,
                              void* d_out, int out_size, void* d_ws, size_t ws_size,
                              hipStream_t stream) {
  const float* x = (const float*)d_in[0];
  const float* t = (const float*)d_in[1];
  const float* Wq = (const float*)d_in[2];
  const float* Wk = (const float*)d_in[3];
  const float* theta = (const float*)d_in[4];
  const float* mu = (const float*)d_in[5];
  float* out = (float*)d_out;

  uint4* qF = (uint4*)d_ws;                             // 8.4 MB (frag-major)
  uint4* kF = qF + (size_t)2048 * 4 * 64;               // 8.4 MB (frag-major)
  ushort_t* wt_g = (ushort_t*)(kF + (size_t)2048 * 4 * 64);  // 64 KB
  float* w = (float*)(wt_g + 256 * 128);                // 128 KB
  float* l = w + (size_t)BB * SS;                       // 128 KB

  hipMemsetAsync(w, 0, (size_t)BB * SS * sizeof(float), stream);
  hipMemsetAsync(l, 0, (size_t)BB * SS * sizeof(float), stream);
  hipMemsetAsync(d_out, 0, (size_t)BB * DD * sizeof(float), stream);

  wprep<<<dim3(128), dim3(256), 0, stream>>>(Wq, Wk, wt_g);
  qk_gemm<<<dim3(512), dim3(256), 0, stream>>>(x, wt_g, qF, kF);
  attn_p1<<<dim3(1024), dim3(256), 0, stream>>>(qF, kF, l);
  attn_p2<<<dim3(1024), dim3(256), 0, stream>>>(qF, kF, t, theta, mu, l, w);
  finalize<<<dim3(512), dim3(256), 0, stream>>>(x, w, out);
}

// Round 7
// 148.067 us; speedup vs baseline: 1.2275x; 1.2275x over previous
//
#include <hip/hip_runtime.h>
#include <hip/hip_bf16.h>

#define SS 2048
#define DD 128
#define BB 16
#define LDST 136  // xs staging pad (ushorts)
#define SCT 268   // sc stride: 4-way max on frag-order epilogue reads

typedef short bf16x8 __attribute__((ext_vector_type(8)));
typedef float f32x4 __attribute__((ext_vector_type(4)));
typedef unsigned short ushort_t;

__device__ __forceinline__ unsigned short f2bf(float f) {
  union { float f; unsigned u; } v; v.f = f;
  unsigned r = v.u + 0x7fffu + ((v.u >> 16) & 1u);  // RNE
  return (unsigned short)(r >> 16);
}
__device__ __forceinline__ float fexp2(float x) { return __builtin_amdgcn_exp2f(x); }

// Fragment-major layout: chunk index ((G*4 + ks)*64 + lane), 16 B each.
// G = global 16-row group (b*128 + g), lane = quad*16 + lq holds
// rows[G*16+lq], cols[ks*32+quad*8 .. +8]. A and B frag loads are then
// one coalesced dwordx4 per (G,ks): lane L reads chunk base + L*16.

// ---------------------------------------------------------------------------
// wprep: wt_g = [Wq^T * log2e/sqrt(U) ; Wk^T] bf16 [256][128]. grid 128.
// ---------------------------------------------------------------------------
__global__ __launch_bounds__(256) void wprep(
    const float* __restrict__ Wq, const float* __restrict__ Wk,
    ushort_t* __restrict__ wt_g) {
  int idx = blockIdx.x * 256 + threadIdx.x;  // 0..32767
  int r = idx & 16383, uu = r >> 7, d = r & 127;
  if (idx < 16384)
    wt_g[uu * 128 + d] = f2bf(Wq[d * 128 + uu] * 0.1275174346f);  // log2e/sqrt(128)
  else
    wt_g[(uu + 128) * 128 + d] = f2bf(Wk[d * 128 + uu]);
}

// ---------------------------------------------------------------------------
// qk_gemm: [q|k] = bf16(x) @ wt_g^T, output in FRAG-MAJOR layout.
// grid 512 (64 rows/block), block 256.
// ---------------------------------------------------------------------------
__global__ __launch_bounds__(256, 2) void qk_gemm(
    const float* __restrict__ x, const ushort_t* __restrict__ wt_g,
    uint4* __restrict__ qF, uint4* __restrict__ kF) {
  __shared__ ushort_t xs[64 * LDST];
  __shared__ ushort_t sc[64 * SCT];
  const int tid = threadIdx.x, wave = tid >> 6, lane = tid & 63;
  const int lq = lane & 15, quad = lane >> 4;
  const int m0 = blockIdx.x * 64;

#pragma unroll
  for (int i = 0; i < 8; ++i) {  // stage x: 64x128 fp32 -> bf16
    int idx = i * 256 + tid;
    int row = idx >> 5, c4 = (idx & 31) * 4;
    const float4 v = *(const float4*)(x + (size_t)(m0 + row) * DD + c4);
    ushort4 h;
    h.x = f2bf(v.x); h.y = f2bf(v.y); h.z = f2bf(v.z); h.w = f2bf(v.w);
    *(ushort4*)(&xs[row * LDST + c4]) = h;
  }
  bf16x8 wf[4][4];  // wave's 64 output cols, K=128
#pragma unroll
  for (int nt = 0; nt < 4; ++nt)
#pragma unroll
    for (int ks = 0; ks < 4; ++ks)
      wf[nt][ks] = *(const bf16x8*)(wt_g + (wave * 64 + nt * 16 + lq) * 128 + ks * 32 + quad * 8);
  __syncthreads();

  f32x4 acc[4][4];
#pragma unroll
  for (int mt = 0; mt < 4; ++mt)
#pragma unroll
    for (int nt = 0; nt < 4; ++nt) acc[mt][nt] = (f32x4){0.f, 0.f, 0.f, 0.f};
#pragma unroll
  for (int mt = 0; mt < 4; ++mt) {
    bf16x8 af[4];
#pragma unroll
    for (int ks = 0; ks < 4; ++ks)
      af[ks] = *(const bf16x8*)(&xs[(mt * 16 + lq) * LDST + ks * 32 + quad * 8]);
#pragma unroll
    for (int nt = 0; nt < 4; ++nt)
#pragma unroll
      for (int ks = 0; ks < 4; ++ks)
        acc[mt][nt] = __builtin_amdgcn_mfma_f32_16x16x32_bf16(af[ks], wf[nt][ks], acc[mt][nt], 0, 0, 0);
  }
  // C/D: row = mt*16+quad*4+r, col = wave*64+nt*16+lq
#pragma unroll
  for (int mt = 0; mt < 4; ++mt)
#pragma unroll
    for (int nt = 0; nt < 4; ++nt)
#pragma unroll
      for (int r = 0; r < 4; ++r)
        sc[(mt * 16 + quad * 4 + r) * SCT + wave * 64 + nt * 16 + lq] = f2bf(acc[mt][nt][r]);
  __syncthreads();
  // epilogue: re-read in fragment order, store coalesced frag-major chunks
#pragma unroll
  for (int i = 0; i < 8; ++i) {
    int c = i * 256 + tid;                 // 0..2047
    int lane_c = c & 63, ks_c = (c >> 6) & 3, g_c = (c >> 8) & 3, isk = c >> 10;
    int li = lane_c & 15, qd = lane_c >> 4;
    int col = isk * 128 + ks_c * 32 + qd * 8;
    uint4 v = *(const uint4*)(&sc[(g_c * 16 + li) * SCT + col]);
    size_t G = (size_t)blockIdx.x * 4 + g_c;
    uint4* dst = isk ? kF : qF;
    dst[(G * 4 + ks_c) * 64 + lane_c] = v;
  }
}

// ---------------------------------------------------------------------------
// attn pass 1 & 2 — K BROADCAST THROUGH LDS, waves partition i.
//
// R6 post-mortem: 128 i-rows/wave doubled per-wave state and spilled at
// the 128-reg cap (VGPR=64 arch, WRITE_SIZE 157 MB). Only spill-safe
// point is the 256-reg budget (2 waves/SIMD, launch_bounds(256,2)):
// R1's af-in-regs shape measured VGPR=104, no spill.
//
// So traffic is cut by SHARING instead: block = 4 waves x 64 i-rows
// (256 rows), each wave holds its own Q frags (64 regs); K tiles staged
// once per block into LDS (reg-staged, double-buffered 2x16 KB, single
// barrier per step -- race-free since write targets buf[st&1] while
// sibling compute uses buf[st&1^1]) and consumed by all 4 waves.
// K traffic/pass: 268 MB -> 64 MB (+32 MB Q re-reads). Per-wave regs:
// af 64 + stage 16 + a 16 + f 16 + rowsum|creg 16 + misc ~ 145 < 256.
// Grid 512 = 16 b x 8 ii x 4 jq, XCD-clustered (b -> XCD b&7); waves own
// disjoint i-rows -> rowsum goes straight to atomicAdd, no LDS reduce.
// ---------------------------------------------------------------------------
__device__ __forceinline__ void attn_decode(int bx, int& b, int& ii, int& jq) {
  int x = bx & 7, s = bx >> 3;   // dispatcher: wgid%8 -> XCD
  b = x + ((s >> 5) << 3);       // XCD x hosts batches x, x+8
  int r = s & 31;
  ii = r >> 2;                   // i-block 0..7 (256 rows each)
  jq = r & 3;                    // j-quarter 0..3 (32 groups = 512 j)
}

__global__ __launch_bounds__(256, 2) void attn_p1(
    const uint4* __restrict__ qF, const uint4* __restrict__ kF,
    float* __restrict__ l) {
  int b, ii, jq;
  attn_decode(blockIdx.x, b, ii, jq);
  const int tid = threadIdx.x, wave = tid >> 6, lane = tid & 63;
  const int lq = lane & 15, quad = lane >> 4;
  __shared__ uint4 kbuf[2][1024];  // 2 x 16 KB (4 j-groups per step)

  // Q frags for this wave's 64 i-rows (groups ii*16 + wave*4 + mt)
  const bf16x8* qc = (const bf16x8*)qF;
  bf16x8 af[4][4];
#pragma unroll
  for (int mt = 0; mt < 4; ++mt)
#pragma unroll
    for (int ks = 0; ks < 4; ++ks)
      af[mt][ks] = qc[((size_t)(b * 128 + ii * 16 + wave * 4 + mt) * 4 + ks) * 64 + lane];

  // K source: groups jq*32 .. +32, 16 KB contiguous per 4-group step
  const uint4* kbase = kF + (size_t)(b * 128 + jq * 32) * 4 * 64;
  uint4 st_r[4];
  auto issue_load = [&](int st) {
#pragma unroll
    for (int i = 0; i < 4; ++i) st_r[i] = kbase[(size_t)st * 1024 + i * 256 + tid];
  };
  auto write_lds = [&](int buf) {
#pragma unroll
    for (int i = 0; i < 4; ++i) kbuf[buf][i * 256 + tid] = st_r[i];
  };

  float rowsum[4][4];
#pragma unroll
  for (int mt = 0; mt < 4; ++mt)
#pragma unroll
    for (int r = 0; r < 4; ++r) rowsum[mt][r] = 0.f;

  const f32x4 z4 = {0.f, 0.f, 0.f, 0.f};
  issue_load(0);
  for (int st = 0; st < 8; ++st) {
    const int cur = st & 1;
    write_lds(cur);
    if (st < 7) issue_load(st + 1);  // in flight across the compute phase
    __syncthreads();
#pragma unroll
    for (int g2 = 0; g2 < 4; ++g2) {
      bf16x8 f[4];
#pragma unroll
      for (int ks = 0; ks < 4; ++ks)
        f[ks] = *(const bf16x8*)&kbuf[cur][(g2 * 4 + ks) * 64 + lane];
      f32x4 a[4];
      __builtin_amdgcn_s_setprio(1);
#pragma unroll
      for (int mt = 0; mt < 4; ++mt)
        a[mt] = __builtin_amdgcn_mfma_f32_16x16x32_bf16(af[mt][0], f[0], z4, 0, 0, 0);
#pragma unroll
      for (int ks = 1; ks < 4; ++ks)
#pragma unroll
        for (int mt = 0; mt < 4; ++mt)
          a[mt] = __builtin_amdgcn_mfma_f32_16x16x32_bf16(af[mt][ks], f[ks], a[mt], 0, 0, 0);
      __builtin_amdgcn_s_setprio(0);
#pragma unroll
      for (int mt = 0; mt < 4; ++mt)
#pragma unroll
        for (int r = 0; r < 4; ++r) rowsum[mt][r] += fexp2(a[mt][r]);
    }
    __syncthreads();  // all waves done with kbuf[cur] before it is rewritten
  }

  // reduce over the 16 j-cols held across lq lanes; each i-row owned by
  // exactly one wave -> straight atomicAdd (accumulates across jq blocks)
#pragma unroll
  for (int d2 = 1; d2 <= 8; d2 <<= 1)
#pragma unroll
    for (int mt = 0; mt < 4; ++mt)
#pragma unroll
      for (int r = 0; r < 4; ++r)
        rowsum[mt][r] += __shfl_xor(rowsum[mt][r], d2, 64);
  if (lq == 0) {
#pragma unroll
    for (int mt = 0; mt < 4; ++mt)
#pragma unroll
      for (int r = 0; r < 4; ++r)
        atomicAdd(&l[b * SS + ii * 256 + (wave * 4 + mt) * 16 + quad * 4 + r],
                  rowsum[mt][r]);
  }
}

__global__ __launch_bounds__(256, 2) void attn_p2(
    const uint4* __restrict__ qF, const uint4* __restrict__ kF,
    const float* __restrict__ t, const float* __restrict__ theta,
    const float* __restrict__ mu, const float* __restrict__ l,
    float* __restrict__ w) {
  int b, ii, jq;
  attn_decode(blockIdx.x, b, ii, jq);
  const int tid = threadIdx.x, wave = tid >> 6, lane = tid & 63;
  const int lq = lane & 15, quad = lane >> 4;
  __shared__ uint4 kbuf[2][1024];
  __shared__ float c_lds[256];

  {  // c_i = sigmoid(theta - mu*t) / l_i for this block's 256 rows
    int gi = ii * 256 + tid;
    float z = theta[gi] - mu[gi] * t[b * SS + gi];
    float tf = 1.f / (1.f + fexp2(-z * 1.44269504f));
    c_lds[tid] = tf / l[b * SS + gi];
  }

  const bf16x8* qc = (const bf16x8*)qF;
  bf16x8 af[4][4];
#pragma unroll
  for (int mt = 0; mt < 4; ++mt)
#pragma unroll
    for (int ks = 0; ks < 4; ++ks)
      af[mt][ks] = qc[((size_t)(b * 128 + ii * 16 + wave * 4 + mt) * 4 + ks) * 64 + lane];

  const uint4* kbase = kF + (size_t)(b * 128 + jq * 32) * 4 * 64;
  uint4 st_r[4];
  auto issue_load = [&](int st) {
#pragma unroll
    for (int i = 0; i < 4; ++i) st_r[i] = kbase[(size_t)st * 1024 + i * 256 + tid];
  };
  auto write_lds = [&](int buf) {
#pragma unroll
    for (int i = 0; i < 4; ++i) kbuf[buf][i * 256 + tid] = st_r[i];
  };

  issue_load(0);
  __syncthreads();  // c_lds visible
  float creg[4][4];
#pragma unroll
  for (int mt = 0; mt < 4; ++mt)
#pragma unroll
    for (int r = 0; r < 4; ++r)
      creg[mt][r] = c_lds[(wave * 4 + mt) * 16 + quad * 4 + r];

  const f32x4 z4 = {0.f, 0.f, 0.f, 0.f};
  for (int st = 0; st < 8; ++st) {
    const int cur = st & 1;
    write_lds(cur);
    if (st < 7) issue_load(st + 1);
    __syncthreads();
#pragma unroll
    for (int g2 = 0; g2 < 4; ++g2) {
      bf16x8 f[4];
#pragma unroll
      for (int ks = 0; ks < 4; ++ks)
        f[ks] = *(const bf16x8*)&kbuf[cur][(g2 * 4 + ks) * 64 + lane];
      f32x4 a[4];
      __builtin_amdgcn_s_setprio(1);
#pragma unroll
      for (int mt = 0; mt < 4; ++mt)
        a[mt] = __builtin_amdgcn_mfma_f32_16x16x32_bf16(af[mt][0], f[0], z4, 0, 0, 0);
#pragma unroll
      for (int ks = 1; ks < 4; ++ks)
#pragma unroll
        for (int mt = 0; mt < 4; ++mt)
          a[mt] = __builtin_amdgcn_mfma_f32_16x16x32_bf16(af[mt][ks], f[ks], a[mt], 0, 0, 0);
      __builtin_amdgcn_s_setprio(0);
      float cs = 0.f;
#pragma unroll
      for (int mt = 0; mt < 4; ++mt)
#pragma unroll
        for (int r = 0; r < 4; ++r) cs = fmaf(creg[mt][r], fexp2(a[mt][r]), cs);
      cs += __shfl_xor(cs, 16, 64);
      cs += __shfl_xor(cs, 32, 64);
      if (lane < 16)
        atomicAdd(&w[b * SS + (jq * 32 + st * 4 + g2) * 16 + lane], cs);
    }
    __syncthreads();
  }
}

// ---------------------------------------------------------------------------
// finalize: v[b,d] = sum_j w[b,j] * x[b,j,d].  grid 512 (64 j per block).
// ---------------------------------------------------------------------------
__global__ __launch_bounds__(256) void finalize(
    const float* __restrict__ x, const float* __restrict__ w,
    float* __restrict__ out) {
  const int b = blockIdx.x >> 5;
  const int j0 = (blockIdx.x & 31) * 64;
  const int tid = threadIdx.x;
  const int d = tid & 127, jo = tid >> 7;
  float acc = 0.f;
  for (int jj = 0; jj < 32; ++jj) {
    int j = j0 + jj * 2 + jo;
    acc = fmaf(w[b * SS + j], x[((size_t)b * SS + j) * DD + d], acc);
  }
  __shared__ float red[256];
  red[tid] = acc;
  __syncthreads();
  if (tid < 128) atomicAdd(&out[b * DD + tid], red[tid] + red[tid + 128]);
}

extern "C" void kernel_launch(void* const* d_in, const int* in_sizes, int n_in,
                              void* d_out, int out_size, void* d_ws, size_t ws_size,
                              hipStream_t stream) {
  const float* x = (const float*)d_in[0];
  const float* t = (const float*)d_in[1];
  const float* Wq = (const float*)d_in[2];
  const float* Wk = (const float*)d_in[3];
  const float* theta = (const float*)d_in[4];
  const float* mu = (const float*)d_in[5];
  float* out = (float*)d_out;

  uint4* qF = (uint4*)d_ws;                             // 8.4 MB (frag-major)
  uint4* kF = qF + (size_t)2048 * 4 * 64;               // 8.4 MB (frag-major)
  ushort_t* wt_g = (ushort_t*)(kF + (size_t)2048 * 4 * 64);  // 64 KB
  float* w = (float*)(wt_g + 256 * 128);                // 128 KB
  float* l = w + (size_t)BB * SS;                       // 128 KB

  hipMemsetAsync(w, 0, (size_t)BB * SS * sizeof(float), stream);
  hipMemsetAsync(l, 0, (size_t)BB * SS * sizeof(float), stream);
  hipMemsetAsync(d_out, 0, (size_t)BB * DD * sizeof(float), stream);

  wprep<<<dim3(128), dim3(256), 0, stream>>>(Wq, Wk, wt_g);
  qk_gemm<<<dim3(512), dim3(256), 0, stream>>>(x, wt_g, qF, kF);
  attn_p1<<<dim3(512), dim3(256), 0, stream>>>(qF, kF, l);
  attn_p2<<<dim3(512), dim3(256), 0, stream>>>(qF, kF, t, theta, mu, l, w);
  finalize<<<dim3(512), dim3(256), 0, stream>>>(x, w, out);
}

// Round 8
// 127.233 us; speedup vs baseline: 1.4285x; 1.1637x over previous
//
#include <hip/hip_runtime.h>
#include <hip/hip_bf16.h>

#define SS 2048
#define DD 128
#define BB 16
#define LDST 136  // xs staging pad (ushorts)
#define SCT 268   // sc stride: 4-way max on frag-order epilogue reads

typedef short bf16x8 __attribute__((ext_vector_type(8)));
typedef float f32x4 __attribute__((ext_vector_type(4)));
typedef unsigned short ushort_t;

#define SB0() __builtin_amdgcn_sched_barrier(0)
#define WAITV(n) asm volatile("s_waitcnt vmcnt(" #n ")" ::: "memory")

__device__ __forceinline__ unsigned short f2bf(float f) {
  union { float f; unsigned u; } v; v.f = f;
  unsigned r = v.u + 0x7fffu + ((v.u >> 16) & 1u);  // RNE
  return (unsigned short)(r >> 16);
}
__device__ __forceinline__ float fexp2(float x) { return __builtin_amdgcn_exp2f(x); }

// Fragment-major layout: chunk index ((G*4 + ks)*64 + lane), 16 B each.
// G = global 16-row group (b*128 + g), lane = quad*16 + lq holds
// rows[G*16+lq], cols[ks*32+quad*8 .. +8].

// ---------------------------------------------------------------------------
// wprep: wt_g = [Wq^T * log2e/sqrt(U) ; Wk^T] bf16 [256][128]. grid 128.
// ---------------------------------------------------------------------------
__global__ __launch_bounds__(256) void wprep(
    const float* __restrict__ Wq, const float* __restrict__ Wk,
    ushort_t* __restrict__ wt_g) {
  int idx = blockIdx.x * 256 + threadIdx.x;  // 0..32767
  int r = idx & 16383, uu = r >> 7, d = r & 127;
  if (idx < 16384)
    wt_g[uu * 128 + d] = f2bf(Wq[d * 128 + uu] * 0.1275174346f);  // log2e/sqrt(128)
  else
    wt_g[(uu + 128) * 128 + d] = f2bf(Wk[d * 128 + uu]);
}

// ---------------------------------------------------------------------------
// qk_gemm: [q|k] = bf16(x) @ wt_g^T, output in FRAG-MAJOR layout.
// grid 512 (64 rows/block), block 256.  (unchanged this round)
// ---------------------------------------------------------------------------
__global__ __launch_bounds__(256, 2) void qk_gemm(
    const float* __restrict__ x, const ushort_t* __restrict__ wt_g,
    uint4* __restrict__ qF, uint4* __restrict__ kF) {
  __shared__ ushort_t xs[64 * LDST];
  __shared__ ushort_t sc[64 * SCT];
  const int tid = threadIdx.x, wave = tid >> 6, lane = tid & 63;
  const int lq = lane & 15, quad = lane >> 4;
  const int m0 = blockIdx.x * 64;

#pragma unroll
  for (int i = 0; i < 8; ++i) {  // stage x: 64x128 fp32 -> bf16
    int idx = i * 256 + tid;
    int row = idx >> 5, c4 = (idx & 31) * 4;
    const float4 v = *(const float4*)(x + (size_t)(m0 + row) * DD + c4);
    ushort4 h;
    h.x = f2bf(v.x); h.y = f2bf(v.y); h.z = f2bf(v.z); h.w = f2bf(v.w);
    *(ushort4*)(&xs[row * LDST + c4]) = h;
  }
  bf16x8 wf[4][4];  // wave's 64 output cols, K=128
#pragma unroll
  for (int nt = 0; nt < 4; ++nt)
#pragma unroll
    for (int ks = 0; ks < 4; ++ks)
      wf[nt][ks] = *(const bf16x8*)(wt_g + (wave * 64 + nt * 16 + lq) * 128 + ks * 32 + quad * 8);
  __syncthreads();

  f32x4 acc[4][4];
#pragma unroll
  for (int mt = 0; mt < 4; ++mt)
#pragma unroll
    for (int nt = 0; nt < 4; ++nt) acc[mt][nt] = (f32x4){0.f, 0.f, 0.f, 0.f};
#pragma unroll
  for (int mt = 0; mt < 4; ++mt) {
    bf16x8 af[4];
#pragma unroll
    for (int ks = 0; ks < 4; ++ks)
      af[ks] = *(const bf16x8*)(&xs[(mt * 16 + lq) * LDST + ks * 32 + quad * 8]);
#pragma unroll
    for (int nt = 0; nt < 4; ++nt)
#pragma unroll
      for (int ks = 0; ks < 4; ++ks)
        acc[mt][nt] = __builtin_amdgcn_mfma_f32_16x16x32_bf16(af[ks], wf[nt][ks], acc[mt][nt], 0, 0, 0);
  }
#pragma unroll
  for (int mt = 0; mt < 4; ++mt)
#pragma unroll
    for (int nt = 0; nt < 4; ++nt)
#pragma unroll
      for (int r = 0; r < 4; ++r)
        sc[(mt * 16 + quad * 4 + r) * SCT + wave * 64 + nt * 16 + lq] = f2bf(acc[mt][nt][r]);
  __syncthreads();
#pragma unroll
  for (int i = 0; i < 8; ++i) {
    int c = i * 256 + tid;                 // 0..2047
    int lane_c = c & 63, ks_c = (c >> 6) & 3, g_c = (c >> 8) & 3, isk = c >> 10;
    int li = lane_c & 15, qd = lane_c >> 4;
    int col = isk * 128 + ks_c * 32 + qd * 8;
    uint4 v = *(const uint4*)(&sc[(g_c * 16 + li) * SCT + col]);
    size_t G = (size_t)blockIdx.x * 4 + g_c;
    uint4* dst = isk ? kF : qF;
    dst[(G * 4 + ks_c) * 64 + lane_c] = v;
  }
}

// ---------------------------------------------------------------------------
// attn_fused: both passes, direct frag-major loads, NO staging barriers.
// grid 512 = 16 b x 32 ib (XCD-chunked), block 256 (4 waves); wave w owns
// groups G(m) = (m>>1)*8 + 2w + (m&1), m in [0,32).
//
// R7 post-mortem: LDS-broadcast (4x less traffic) was SLOWER (64 vs 44
// us pair) -> traffic volume is not binding; the barrier-free direct
// stream is right and its limiter is exposed load latency. R1's source
// ping-pong was re-serialized by the compiler (VGPR 84). This version
// forces a depth-2 pipeline at ISA level: 8 K-loads in flight, counted
// s_waitcnt vmcnt(4) + sched_barrier(0) before each consume (never
// drains to 0 mid-loop -- T4). XCD-chunk map gives the FETCH readout.
// Regs: af 64 + fA/fB 32 + a 16 + rowsum|creg 16 + misc ~ 145 < 256.
// ---------------------------------------------------------------------------
__global__ __launch_bounds__(256, 2) void attn_fused(
    const uint4* __restrict__ qF, const uint4* __restrict__ kF,
    const float* __restrict__ t, const float* __restrict__ theta,
    const float* __restrict__ mu, float* __restrict__ w) {
  // XCD-chunked decode: dispatcher assigns wgid%8 -> XCD; batch b lives
  // on XCD b&7 (working set 2 batches x 1 MB < 4 MB L2).
  const int xcd = blockIdx.x & 7, s = blockIdx.x >> 3;  // s in [0,64)
  const int b = xcd + ((s >> 5) << 3);
  const int ib = s & 31;
  const int i0 = ib * 64;
  const int tid = threadIdx.x, wave = tid >> 6, lane = tid & 63;
  const int lq = lane & 15, quad = lane >> 4;

  __shared__ float rs_lds[4][64];
  __shared__ float c_lds[64];

  const bf16x8* qc = (const bf16x8*)qF;

  // A frags: 64 q-rows x K=128 (held across BOTH passes)
  bf16x8 af[4][4];
#pragma unroll
  for (int mt = 0; mt < 4; ++mt)
#pragma unroll
    for (int ks = 0; ks < 4; ++ks)
      af[mt][ks] = qc[((size_t)(b * 128 + ib * 4 + mt) * 4 + ks) * 64 + lane];

  const bf16x8* kb = (const bf16x8*)kF + (size_t)b * 128 * 4 * 64 + lane;
  auto loadg = [&](bf16x8 (&f)[4], int g) {
#pragma unroll
    for (int ks = 0; ks < 4; ++ks)
      f[ks] = kb[((size_t)g * 4 + ks) * 64];
  };
  auto G = [&](int m) { return (m >> 1) * 8 + wave * 2 + (m & 1); };

  const f32x4 z4 = {0.f, 0.f, 0.f, 0.f};
  auto mfma16 = [&](f32x4 (&a)[4], bf16x8 (&f)[4]) {
    __builtin_amdgcn_s_setprio(1);
#pragma unroll
    for (int mt = 0; mt < 4; ++mt)
      a[mt] = __builtin_amdgcn_mfma_f32_16x16x32_bf16(af[mt][0], f[0], z4, 0, 0, 0);
#pragma unroll
    for (int ks = 1; ks < 4; ++ks)
#pragma unroll
      for (int mt = 0; mt < 4; ++mt)
        a[mt] = __builtin_amdgcn_mfma_f32_16x16x32_bf16(af[mt][ks], f[ks], a[mt], 0, 0, 0);
    __builtin_amdgcn_s_setprio(0);
  };

  float rowsum[4][4];
#pragma unroll
  for (int mt = 0; mt < 4; ++mt)
#pragma unroll
    for (int r = 0; r < 4; ++r) rowsum[mt][r] = 0.f;
  auto proc1 = [&](f32x4 (&a)[4]) {
#pragma unroll
    for (int mt = 0; mt < 4; ++mt)
#pragma unroll
      for (int r = 0; r < 4; ++r) rowsum[mt][r] += fexp2(a[mt][r]);
  };

  bf16x8 fA[4], fB[4];
  f32x4 a[4];

  // ---- PASS 1: row sums (depth-2 counted-vmcnt pipeline) ----
  loadg(fA, G(0));
  loadg(fB, G(1));                       // 8 loads in flight
  for (int m = 0; m < 30; m += 2) {
    WAITV(4); SB0();                     // oldest 4 (fA) landed
    mfma16(a, fA);
    loadg(fA, G(m + 2)); SB0();          // refill while exp2 runs
    proc1(a);
    WAITV(4); SB0();
    mfma16(a, fB);
    loadg(fB, G(m + 3)); SB0();
    proc1(a);
  }
  WAITV(4); SB0(); mfma16(a, fA); SB0(); proc1(a);
  WAITV(0); SB0(); mfma16(a, fB); SB0(); proc1(a);

#pragma unroll
  for (int d2 = 1; d2 <= 8; d2 <<= 1)
#pragma unroll
    for (int mt = 0; mt < 4; ++mt)
#pragma unroll
      for (int r = 0; r < 4; ++r)
        rowsum[mt][r] += __shfl_xor(rowsum[mt][r], d2, 64);
  if (lq == 0) {
#pragma unroll
    for (int mt = 0; mt < 4; ++mt)
#pragma unroll
      for (int r = 0; r < 4; ++r)
        rs_lds[wave][mt * 16 + quad * 4 + r] = rowsum[mt][r];
  }
  __syncthreads();
  if (tid < 64) {
    float l = rs_lds[0][tid] + rs_lds[1][tid] + rs_lds[2][tid] + rs_lds[3][tid];
    int gi = i0 + tid;
    float z = theta[gi] - mu[gi] * t[b * SS + gi];
    float tf = 1.f / (1.f + fexp2(-z * 1.44269504f));
    c_lds[tid] = tf / l;
  }
  __syncthreads();
  float creg[4][4];
#pragma unroll
  for (int mt = 0; mt < 4; ++mt)
#pragma unroll
    for (int r = 0; r < 4; ++r) creg[mt][r] = c_lds[mt * 16 + quad * 4 + r];

  auto proc2 = [&](f32x4 (&aa)[4], int g) {
    float cs = 0.f;
#pragma unroll
    for (int mt = 0; mt < 4; ++mt)
#pragma unroll
      for (int r = 0; r < 4; ++r) cs = fmaf(creg[mt][r], fexp2(aa[mt][r]), cs);
    cs += __shfl_xor(cs, 16, 64);
    cs += __shfl_xor(cs, 32, 64);
    if (lane < 16) atomicAdd(&w[b * SS + g * 16 + lane], cs);
  };

  // ---- PASS 2: column sums -> w (same pipeline; af reused) ----
  loadg(fA, G(0));
  loadg(fB, G(1));
  for (int m = 0; m < 30; m += 2) {
    WAITV(4); SB0();
    mfma16(a, fA);
    loadg(fA, G(m + 2)); SB0();
    proc2(a, G(m));
    WAITV(4); SB0();
    mfma16(a, fB);
    loadg(fB, G(m + 3)); SB0();
    proc2(a, G(m + 1));
  }
  WAITV(4); SB0(); mfma16(a, fA); SB0(); proc2(a, G(30));
  WAITV(0); SB0(); mfma16(a, fB); SB0(); proc2(a, G(31));
}

// ---------------------------------------------------------------------------
// finalize: v[b,d] = sum_j w[b,j] * x[b,j,d].  grid 512 (64 j per block).
// Vectorized: float4 x loads (16B/lane), 2 independent accumulators,
// float4 LDS tree reduce over jo.
// ---------------------------------------------------------------------------
__global__ __launch_bounds__(256) void finalize(
    const float* __restrict__ x, const float* __restrict__ w,
    float* __restrict__ out) {
  const int b = blockIdx.x >> 5;
  const int j0 = (blockIdx.x & 31) * 64;
  const int tid = threadIdx.x;
  const int d4 = (tid & 31) * 4, jo = tid >> 5;  // 32 d-groups x 8 j-offsets
  float4 a0 = {0.f, 0.f, 0.f, 0.f}, a1 = {0.f, 0.f, 0.f, 0.f};
#pragma unroll
  for (int jj = 0; jj < 4; ++jj) {
    int ja = j0 + jj * 16 + jo, jb = ja + 8;
    float wa = w[b * SS + ja], wb = w[b * SS + jb];
    const float4 xa = *(const float4*)(x + ((size_t)b * SS + ja) * DD + d4);
    const float4 xb = *(const float4*)(x + ((size_t)b * SS + jb) * DD + d4);
    a0.x = fmaf(wa, xa.x, a0.x); a0.y = fmaf(wa, xa.y, a0.y);
    a0.z = fmaf(wa, xa.z, a0.z); a0.w = fmaf(wa, xa.w, a0.w);
    a1.x = fmaf(wb, xb.x, a1.x); a1.y = fmaf(wb, xb.y, a1.y);
    a1.z = fmaf(wb, xb.z, a1.z); a1.w = fmaf(wb, xb.w, a1.w);
  }
  __shared__ float4 red[256];
  float4 acc = {a0.x + a1.x, a0.y + a1.y, a0.z + a1.z, a0.w + a1.w};
  red[tid] = acc;
  __syncthreads();
  if (tid < 128) {
    float4 o = red[tid + 128];
    red[tid].x += o.x; red[tid].y += o.y; red[tid].z += o.z; red[tid].w += o.w;
  }
  __syncthreads();
  if (tid < 64) {
    float4 o = red[tid + 64];
    red[tid].x += o.x; red[tid].y += o.y; red[tid].z += o.z; red[tid].w += o.w;
  }
  __syncthreads();
  if (tid < 32) {
    float4 v = red[tid], o = red[tid + 32];
    v.x += o.x; v.y += o.y; v.z += o.z; v.w += o.w;
    atomicAdd(&out[b * DD + d4 + 0], v.x);
    atomicAdd(&out[b * DD + d4 + 1], v.y);
    atomicAdd(&out[b * DD + d4 + 2], v.z);
    atomicAdd(&out[b * DD + d4 + 3], v.w);
  }
}

extern "C" void kernel_launch(void* const* d_in, const int* in_sizes, int n_in,
                              void* d_out, int out_size, void* d_ws, size_t ws_size,
                              hipStream_t stream) {
  const float* x = (const float*)d_in[0];
  const float* t = (const float*)d_in[1];
  const float* Wq = (const float*)d_in[2];
  const float* Wk = (const float*)d_in[3];
  const float* theta = (const float*)d_in[4];
  const float* mu = (const float*)d_in[5];
  float* out = (float*)d_out;

  uint4* qF = (uint4*)d_ws;                             // 8.4 MB (frag-major)
  uint4* kF = qF + (size_t)2048 * 4 * 64;               // 8.4 MB (frag-major)
  ushort_t* wt_g = (ushort_t*)(kF + (size_t)2048 * 4 * 64);  // 64 KB
  float* w = (float*)(wt_g + 256 * 128);                // 128 KB

  hipMemsetAsync(w, 0, (size_t)BB * SS * sizeof(float), stream);
  hipMemsetAsync(d_out, 0, (size_t)BB * DD * sizeof(float), stream);

  wprep<<<dim3(128), dim3(256), 0, stream>>>(Wq, Wk, wt_g);
  qk_gemm<<<dim3(512), dim3(256), 0, stream>>>(x, wt_g, qF, kF);
  attn_fused<<<dim3(512), dim3(256), 0, stream>>>(qF, kF, t, theta, mu, w);
  finalize<<<dim3(512), dim3(256), 0, stream>>>(x, w, out);
}